// Round 7
// baseline (156.021 us; speedup 1.0000x reference)
//
#include <hip/hip_runtime.h>

#define F_IN  128
#define H_MID 16
#define C_OUT 8
#define XS_PAD (F_IN + 4)
#define TROWS 32            // gemm1 tile rows (double-buffered)
#define CHUNK 4096          // edges per k_bscatter block
#define NBMAX 512           // bucket array size (NB = ceil(N/256) <= 512)

// ---- zero bcount without hipMemsetAsync (a 2KB fillBufferAligned cost ~39us in graph) ----
__global__ void __launch_bounds__(512) k_zero512(int* __restrict__ p) {
    p[threadIdx.x] = 0;
}

// ======================================================================
// Bucketed counting-sort CSR build (atomic-light).
// Bucket of dst d = d>>8 (256 dst per bucket). Edge record packed as
// int2 { src | (d&255)<<18 , float_bits(ew) }  -- requires N <= 131072.
// ======================================================================

__global__ void __launch_bounds__(256) k_bhist(const int* __restrict__ dst,
                                               int* __restrict__ bcount,
                                               int E, int NB) {
    __shared__ int hist[NBMAX];
    const int t = threadIdx.x;
    for (int l = t; l < NBMAX; l += 256) hist[l] = 0;
    __syncthreads();
    for (int i = blockIdx.x * 256 + t; i < E; i += gridDim.x * 256)
        atomicAdd(&hist[((unsigned)dst[i]) >> 8], 1);
    __syncthreads();
    for (int l = t; l < NB; l += 256)
        if (hist[l]) atomicAdd(&bcount[l], hist[l]);
}

__global__ void __launch_bounds__(512) k_bscan(const int* __restrict__ bcount,
                                               int* __restrict__ bptr,
                                               int* __restrict__ bcursor,
                                               int NB, int E) {
    __shared__ int s[512];
    const int t = threadIdx.x;
    const int v = (t < NB) ? bcount[t] : 0;
    s[t] = v;
    __syncthreads();
#pragma unroll
    for (int off = 1; off < 512; off <<= 1) {
        int u = (t >= off) ? s[t - off] : 0;
        __syncthreads();
        s[t] += u;
        __syncthreads();
    }
    if (t < NB) {
        const int excl = s[t] - v;
        bptr[t] = excl;
        bcursor[t] = excl;
    }
    if (t == NB - 1) bptr[NB] = E;
}

__global__ void __launch_bounds__(256) k_bscatter(
        const int* __restrict__ src, const int* __restrict__ dst,
        const float* __restrict__ ew, const int* __restrict__ bptr,
        int* __restrict__ bcursor, int2* __restrict__ bed, int E, int NB) {
    __shared__ int hist[NBMAX], scn[NBMAX], cur[NBMAX], base[NBMAX];
    __shared__ int2 sorted[CHUNK];
    __shared__ unsigned short bof[CHUNK];
    const int t = threadIdx.x;
    const int c0 = blockIdx.x * CHUNK;
    const int n = (E - c0 < CHUNK) ? (E - c0) : CHUNK;

    for (int l = t; l < NBMAX; l += 256) hist[l] = 0;
    __syncthreads();
    for (int i = t; i < n; i += 256)
        atomicAdd(&hist[((unsigned)dst[c0 + i]) >> 8], 1);
    __syncthreads();
    scn[t] = hist[t];
    scn[t + 256] = hist[t + 256];
    __syncthreads();
#pragma unroll
    for (int off = 1; off < 512; off <<= 1) {
        const int i1 = t + 256;
        const int v0 = (t >= off) ? scn[t - off] : 0;
        const int v1 = scn[i1 - off];
        __syncthreads();
        scn[t] += v0;
        scn[i1] += v1;
        __syncthreads();
    }
    cur[t] = scn[t] - hist[t];
    cur[t + 256] = scn[t + 256] - hist[t + 256];
    __syncthreads();
    for (int i = t; i < n; i += 256) {
        const int s  = src[c0 + i];
        const int d  = dst[c0 + i];
        const float w = ew[c0 + i];
        const int bk = ((unsigned)d) >> 8;
        const int slot = atomicAdd(&cur[bk], 1);
        sorted[slot] = make_int2(s | ((d & 255) << 18), __float_as_int(w));
        bof[slot] = (unsigned short)bk;
    }
    __syncthreads();
    for (int l = t; l < NB; l += 256)
        base[l] = hist[l] ? atomicAdd(&bcursor[l], hist[l]) : 0;
    __syncthreads();
    for (int i = t; i < n; i += 256) {
        const int bk = bof[i];
        const int excl = scn[bk] - hist[bk];
        bed[base[bk] + (i - excl)] = sorted[i];
    }
}

// ---- pass C: per-bucket sort -> final ed[], rowptr, dis (LDS int atomics) ----
__global__ void __launch_bounds__(256) k_bsort(
        const int2* __restrict__ bed, const int* __restrict__ bptr,
        int* __restrict__ rowptr, float* __restrict__ dis,
        int2* __restrict__ ed, int N, int E, int NB) {
    __shared__ int hist[256], scn[256], cur[256];
    __shared__ float degw[256];
    const int t = threadIdx.x;
    const int b = blockIdx.x;
    const int r0 = b << 8;
    const int L = (N - r0 < 256) ? (N - r0) : 256;
    const int e0 = bptr[b];
    const int M = bptr[b + 1] - e0;

    hist[t] = 0;
    degw[t] = 0.0f;
    __syncthreads();
    for (int i = t; i < M; i += 256) {
        const int2 rec = bed[e0 + i];
        const int dl = ((unsigned)rec.x) >> 18;
        atomicAdd(&hist[dl], 1);
        atomicAdd(&degw[dl], __int_as_float(rec.y));
    }
    __syncthreads();
    scn[t] = hist[t];
    __syncthreads();
#pragma unroll
    for (int off = 1; off < 256; off <<= 1) {
        int u = (t >= off) ? scn[t - off] : 0;
        __syncthreads();
        scn[t] += u;
        __syncthreads();
    }
    const int excl = scn[t] - hist[t];
    if (t < L) {
        rowptr[r0 + t] = e0 + excl;
        dis[r0 + t] = rsqrtf(1.0f + degw[t]);   // self-loop weight 1 => deg >= 1
    }
    cur[t] = excl;
    __syncthreads();
    for (int i = t; i < M; i += 256) {
        const int2 rec = bed[e0 + i];
        const int dl = ((unsigned)rec.x) >> 18;
        const int slot = atomicAdd(&cur[dl], 1);
        ed[e0 + slot] = make_int2(rec.x & 0x3FFFF, rec.y);
    }
    if (b == 0 && t == 0) rowptr[N] = E;
}

// ======================================================================
// Compute kernels (factorized norm: h rows pre-scaled by dis[row])
// ======================================================================

// h1s = (x @ W1) * dis[row] — persistent, double-buffered, reg-staged
__global__ void __launch_bounds__(256, 3) k_gemm1(
        const float* __restrict__ x, const float* __restrict__ W1,
        const float* __restrict__ dis, float* __restrict__ h1s, int N) {
    __shared__ float xs[2][TROWS * XS_PAD];
    __shared__ float W1s[F_IN * H_MID];
    const int t = threadIdx.x;
    for (int i = t; i < F_IN * H_MID; i += 256) W1s[i] = W1[i];
    const int c  = t & 15;
    const int r0 = t >> 4;                 // 0..15; thread owns rows r0, r0+16
    const int ntiles = (N + TROWS - 1) / TROWS;

    float4 st[4];
    auto stage_load = [&](int tile) {
        const float4* xg = reinterpret_cast<const float4*>(x + (long long)tile * TROWS * F_IN);
        const int nfl = ((N - tile * TROWS < TROWS) ? (N - tile * TROWS) : TROWS) * (F_IN / 4);
#pragma unroll
        for (int j = 0; j < 4; ++j) {
            const int i = t + j * 256;
            st[j] = (i < nfl) ? xg[i] : make_float4(0.f, 0.f, 0.f, 0.f);
        }
    };
    auto stage_write = [&](int buf) {
#pragma unroll
        for (int j = 0; j < 4; ++j) {
            const int i = t + j * 256;
            const int r = i >> 5, k4 = i & 31;
            *reinterpret_cast<float4*>(&xs[buf][r * XS_PAD + k4 * 4]) = st[j];
        }
    };

    int tile = blockIdx.x;
    if (tile >= ntiles) return;
    stage_load(tile);
    stage_write(0);
    __syncthreads();
    int buf = 0;
    while (true) {
        const int next = tile + gridDim.x;
        if (next < ntiles) stage_load(next);     // HBM loads in flight during compute
        const float* xr0 = &xs[buf][r0 * XS_PAD];
        const float* xr1 = &xs[buf][(r0 + 16) * XS_PAD];
        float acc0 = 0.0f, acc1 = 0.0f;
#pragma unroll 4
        for (int k4 = 0; k4 < F_IN / 4; ++k4) {
            const float4 v0 = *reinterpret_cast<const float4*>(&xr0[k4 * 4]);
            const float4 v1 = *reinterpret_cast<const float4*>(&xr1[k4 * 4]);
            const float w0 = W1s[(k4 * 4 + 0) * H_MID + c];
            const float w1 = W1s[(k4 * 4 + 1) * H_MID + c];
            const float w2 = W1s[(k4 * 4 + 2) * H_MID + c];
            const float w3 = W1s[(k4 * 4 + 3) * H_MID + c];
            acc0 = fmaf(v0.x, w0, acc0); acc1 = fmaf(v1.x, w0, acc1);
            acc0 = fmaf(v0.y, w1, acc0); acc1 = fmaf(v1.y, w1, acc1);
            acc0 = fmaf(v0.z, w2, acc0); acc1 = fmaf(v1.z, w2, acc1);
            acc0 = fmaf(v0.w, w3, acc0); acc1 = fmaf(v1.w, w3, acc1);
        }
        const long long row0 = (long long)tile * TROWS + r0;
        const long long row1 = row0 + 16;
        if (row0 < N) h1s[row0 * H_MID + c] = acc0 * dis[row0];
        if (row1 < N) h1s[row1 * H_MID + c] = acc1 * dis[row1];
        if (next >= ntiles) break;
        __syncthreads();
        stage_write(buf ^ 1);
        __syncthreads();
        buf ^= 1;
        tile = next;
    }
}

// a1 = relu(b1 + dis[node]*(h[node] + sum_edges h[src]*ew))  — register accum
template <int LOG, bool RELU>
__global__ void k_agg_csr(const int* __restrict__ rowptr, const int2* __restrict__ ed,
                          const float* __restrict__ h, const float* __restrict__ dis,
                          const float* __restrict__ bias, float* __restrict__ out, int N) {
    const int CH = 1 << LOG;
    const long long t = (long long)blockIdx.x * blockDim.x + threadIdx.x;
    const int node = (int)(t >> LOG);
    const int c = (int)(t & (CH - 1));
    if (node >= N) return;
    const int beg = rowptr[node];
    const int end = rowptr[node + 1];
    float acc0 = h[(long long)node * CH + c];   // self loop (weight 1)
    float acc1 = 0.0f;
    int e = beg;
    for (; e + 1 < end; e += 2) {
        int2 p0 = ed[e];
        int2 p1 = ed[e + 1];
        acc0 = fmaf(h[(long long)p0.x * CH + c], __int_as_float(p0.y), acc0);
        acc1 = fmaf(h[(long long)p1.x * CH + c], __int_as_float(p1.y), acc1);
    }
    if (e < end) {
        int2 p = ed[e];
        acc0 = fmaf(h[(long long)p.x * CH + c], __int_as_float(p.y), acc0);
    }
    float r = fmaf(acc0 + acc1, dis[node], bias[c]);
    if (RELU) r = fmaxf(r, 0.0f);
    out[(long long)node * CH + c] = r;
}

// h2s = (a1 @ W2) * dis[row]   (a1 already relu'd)
__global__ void k_gemm2(const float* __restrict__ a1, const float* __restrict__ W2,
                        const float* __restrict__ dis, float* __restrict__ h2s, int N) {
    __shared__ float W2s[H_MID * C_OUT];
    if (threadIdx.x < H_MID * C_OUT) W2s[threadIdx.x] = W2[threadIdx.x];
    __syncthreads();
    const int c   = threadIdx.x & 7;
    const int lr  = threadIdx.x >> 3;
    const int rpb = blockDim.x >> 3;
    for (long long row = (long long)blockIdx.x * rpb + lr; row < N;
         row += (long long)gridDim.x * rpb) {
        const float4* ar = reinterpret_cast<const float4*>(a1 + row * H_MID);
        float acc = 0.0f;
#pragma unroll
        for (int k4 = 0; k4 < H_MID / 4; ++k4) {
            float4 v = ar[k4];
            acc = fmaf(v.x, W2s[(k4 * 4 + 0) * C_OUT + c], acc);
            acc = fmaf(v.y, W2s[(k4 * 4 + 1) * C_OUT + c], acc);
            acc = fmaf(v.z, W2s[(k4 * 4 + 2) * C_OUT + c], acc);
            acc = fmaf(v.w, W2s[(k4 * 4 + 3) * C_OUT + c], acc);
        }
        h2s[row * C_OUT + c] = acc * dis[row];
    }
}

// ======================================================================
// Fallback: atomic pipeline (size-guard escape hatch)
// ======================================================================
__global__ void k_init_deg(float* __restrict__ deg, int N) {
    int i = blockIdx.x * blockDim.x + threadIdx.x;
    if (i < N) deg[i] = 1.0f;
}
__global__ void k_scatter_deg(const int* __restrict__ dst, const float* __restrict__ ew,
                              float* __restrict__ deg, int E) {
    int e = blockIdx.x * blockDim.x + threadIdx.x;
    if (e < E) atomicAdd(&deg[dst[e]], ew[e]);
}
__global__ void k_rsqrt(float* __restrict__ deg, int N) {
    int i = blockIdx.x * blockDim.x + threadIdx.x;
    if (i < N) {
        float v = deg[i];
        deg[i] = (v > 0.0f) ? rsqrtf(v) : 0.0f;
    }
}
__global__ void k_gemm1_r2(const float* __restrict__ x, const float* __restrict__ W1,
                           const float* __restrict__ b1, const float* __restrict__ dis,
                           float* __restrict__ h1, float* __restrict__ a1, int N) {
    __shared__ float W1s[F_IN * H_MID];
    for (int i = threadIdx.x; i < F_IN * H_MID; i += blockDim.x) W1s[i] = W1[i];
    __syncthreads();
    const int c   = threadIdx.x & 15;
    const int lr  = threadIdx.x >> 4;
    const int rpb = blockDim.x >> 4;
    for (long long row = (long long)blockIdx.x * rpb + lr; row < N;
         row += (long long)gridDim.x * rpb) {
        const float4* xr = reinterpret_cast<const float4*>(x + row * F_IN);
        float acc = 0.0f;
#pragma unroll
        for (int k4 = 0; k4 < F_IN / 4; ++k4) {
            float4 v = xr[k4];
            acc = fmaf(v.x, W1s[(k4 * 4 + 0) * H_MID + c], acc);
            acc = fmaf(v.y, W1s[(k4 * 4 + 1) * H_MID + c], acc);
            acc = fmaf(v.z, W1s[(k4 * 4 + 2) * H_MID + c], acc);
            acc = fmaf(v.w, W1s[(k4 * 4 + 3) * H_MID + c], acc);
        }
        h1[row * H_MID + c] = acc;
        float di = dis[row];
        a1[row * H_MID + c] = fmaf(acc, di * di, b1[c]);
    }
}
template <int CH>
__global__ void k_agg_at(const int* __restrict__ src, const int* __restrict__ dst,
                         const float* __restrict__ ew, const float* __restrict__ dis,
                         const float* __restrict__ h, float* __restrict__ out, long long E) {
    const int LOG = (CH == 16) ? 4 : 3;
    const long long total  = E << LOG;
    const long long stride = (long long)gridDim.x * blockDim.x;
    for (long long idx = (long long)blockIdx.x * blockDim.x + threadIdx.x; idx < total;
         idx += stride) {
        const long long e = idx >> LOG;
        const int c = (int)(idx & (CH - 1));
        const int s = src[e];
        const int d = dst[e];
        const float norm = dis[s] * ew[e] * dis[d];
        atomicAdd(out + (long long)d * CH + c, h[(long long)s * CH + c] * norm);
    }
}
__global__ void k_gemm2_r2(const float* __restrict__ a1, const float* __restrict__ W2,
                           const float* __restrict__ b2, const float* __restrict__ dis,
                           float* __restrict__ h2, float* __restrict__ out, int N) {
    __shared__ float W2s[H_MID * C_OUT];
    if (threadIdx.x < H_MID * C_OUT) W2s[threadIdx.x] = W2[threadIdx.x];
    __syncthreads();
    const int c   = threadIdx.x & 7;
    const int lr  = threadIdx.x >> 3;
    const int rpb = blockDim.x >> 3;
    for (long long row = (long long)blockIdx.x * rpb + lr; row < N;
         row += (long long)gridDim.x * rpb) {
        const float4* ar = reinterpret_cast<const float4*>(a1 + row * H_MID);
        float acc = 0.0f;
#pragma unroll
        for (int k4 = 0; k4 < H_MID / 4; ++k4) {
            float4 v = ar[k4];
            acc = fmaf(fmaxf(v.x, 0.0f), W2s[(k4 * 4 + 0) * C_OUT + c], acc);
            acc = fmaf(fmaxf(v.y, 0.0f), W2s[(k4 * 4 + 1) * C_OUT + c], acc);
            acc = fmaf(fmaxf(v.z, 0.0f), W2s[(k4 * 4 + 2) * C_OUT + c], acc);
            acc = fmaf(fmaxf(v.w, 0.0f), W2s[(k4 * 4 + 3) * C_OUT + c], acc);
        }
        h2[row * C_OUT + c] = acc;
        float di = dis[row];
        out[row * C_OUT + c] = fmaf(acc, di * di, b2[c]);
    }
}

extern "C" void kernel_launch(void* const* d_in, const int* in_sizes, int n_in,
                              void* d_out, int out_size, void* d_ws, size_t ws_size,
                              hipStream_t stream) {
    const float* x  = (const float*)d_in[0];
    const int*   ei = (const int*)d_in[1];
    const float* ew = (const float*)d_in[2];
    const float* W1 = (const float*)d_in[3];
    const float* b1 = (const float*)d_in[4];
    const float* W2 = (const float*)d_in[5];
    const float* b2 = (const float*)d_in[6];
    float* out = (float*)d_out;

    const int H   = in_sizes[4];            // 16
    const int Fin = in_sizes[3] / H;        // 128
    const int N   = in_sizes[0] / Fin;      // 100000
    const int E   = in_sizes[2];            // 1600000
    const int* src = ei;
    const int* dst = ei + E;
    (void)n_in; (void)out_size;

    char* ws = (char*)d_ws;
    size_t off = 0;
    auto alloc = [&](size_t bytes) {
        void* p = ws + off;
        off = (off + bytes + 255) & ~(size_t)255;
        return p;
    };
    float* dis    = (float*)alloc((size_t)N * sizeof(float));
    float* h1s    = (float*)alloc((size_t)N * H_MID * sizeof(float));
    int*   rowptr = (int*)alloc(((size_t)N + 1) * sizeof(int));
    int*   bcount = (int*)alloc(NBMAX * sizeof(int));
    int*   bptr   = (int*)alloc((NBMAX + 1) * sizeof(int));
    int*   bcursor= (int*)alloc(NBMAX * sizeof(int));
    int2*  bed    = (int2*)alloc((size_t)E * sizeof(int2));
    int2*  ed     = (int2*)alloc((size_t)E * sizeof(int2));
    // a1 / h2s alias bed (dead after k_bsort, reborn as layer activations)
    float* a1  = (float*)bed;
    float* h2s = (float*)bed + (size_t)N * H_MID;
    const size_t needed = off;

    const int B = 256;
    const int NB = (N + 255) >> 8;
    const bool fast_ok = (needed <= ws_size) && (N <= 131072) && (NB <= NBMAX) &&
                         ((size_t)E * sizeof(int2) >= (size_t)N * (H_MID + C_OUT) * sizeof(float));

    if (fast_ok) {
        // ---- CSR build (bucket partition + per-bucket sort) ----
        k_zero512<<<1, 512, 0, stream>>>(bcount);
        k_bhist<<<512, B, 0, stream>>>(dst, bcount, E, NB);
        k_bscan<<<1, 512, 0, stream>>>(bcount, bptr, bcursor, NB, E);
        k_bscatter<<<(E + CHUNK - 1) / CHUNK, B, 0, stream>>>(
            src, dst, ew, bptr, bcursor, bed, E, NB);
        k_bsort<<<NB, B, 0, stream>>>(bed, bptr, rowptr, dis, ed, N, E, NB);
        // ---- layer 1 ----
        const int ntiles = (N + TROWS - 1) / TROWS;
        const int g1 = (ntiles < 768) ? ntiles : 768;
        k_gemm1<<<g1, B, 0, stream>>>(x, W1, dis, h1s, N);
        k_agg_csr<4, true><<<(int)(((long long)N * H_MID + B - 1) / B), B, 0, stream>>>(
            rowptr, ed, h1s, dis, b1, a1, N);
        // ---- layer 2 ----
        k_gemm2<<<(N + 31) / 32, B, 0, stream>>>(a1, W2, dis, h2s, N);
        k_agg_csr<3, false><<<(int)(((long long)N * C_OUT + B - 1) / B), B, 0, stream>>>(
            rowptr, ed, h2s, dis, b2, out, N);
    } else {
        // ---- fallback: atomic path (~17 MB) ----
        off = 0;
        float* disF = (float*)alloc((size_t)N * sizeof(float));
        float* h1   = (float*)alloc((size_t)N * H_MID * sizeof(float));
        float* a1F  = (float*)alloc((size_t)N * H_MID * sizeof(float));
        float* h2   = (float*)alloc((size_t)N * C_OUT * sizeof(float));
        k_init_deg<<<(N + B - 1) / B, B, 0, stream>>>(disF, N);
        k_scatter_deg<<<(E + B - 1) / B, B, 0, stream>>>(dst, ew, disF, E);
        k_rsqrt<<<(N + B - 1) / B, B, 0, stream>>>(disF, N);
        k_gemm1_r2<<<(N + 15) / 16, B, 0, stream>>>(x, W1, b1, disF, h1, a1F, N);
        k_agg_at<H_MID><<<8192, B, 0, stream>>>(src, dst, ew, disF, h1, a1F, E);
        k_gemm2_r2<<<(N + 31) / 32, B, 0, stream>>>(a1F, W2, b2, disF, h2, out, N);
        k_agg_at<C_OUT><<<8192, B, 0, stream>>>(src, dst, ew, disF, h2, out, E);
    }
}

// Round 8
// 140.953 us; speedup vs baseline: 1.1069x; 1.1069x over previous
//
#include <hip/hip_runtime.h>

#define F_IN  128
#define H_MID 16
#define C_OUT 8
#define XS_PAD (F_IN + 4)
#define TROWS 32            // gemm1 tile rows (double-buffered)
#define CHUNK 4096          // edges per k_bscatter block
#define NBMAX 512           // bucket array size (NB = ceil(N/256) <= 512)

// ---- zero bcount (cheap kernel; avoids fillBuffer in graph) ----
__global__ void __launch_bounds__(512) k_zero512(int* __restrict__ p) {
    p[threadIdx.x] = 0;
}

// ======================================================================
// Bucketed counting-sort CSR build (atomic-light).
// Bucket of dst d = d>>8 (256 dst per bucket). Edge record packed as
// int2 { src | (d&255)<<18 , float_bits(ew) }  -- requires N <= 131072.
// ======================================================================

__global__ void __launch_bounds__(256) k_bhist(const int* __restrict__ dst,
                                               int* __restrict__ bcount,
                                               int E, int NB) {
    __shared__ int hist[NBMAX];
    const int t = threadIdx.x;
    for (int l = t; l < NBMAX; l += 256) hist[l] = 0;
    __syncthreads();
    for (int i = blockIdx.x * 256 + t; i < E; i += gridDim.x * 256)
        atomicAdd(&hist[((unsigned)dst[i]) >> 8], 1);
    __syncthreads();
    for (int l = t; l < NB; l += 256)
        if (hist[l]) atomicAdd(&bcount[l], hist[l]);
}

__global__ void __launch_bounds__(512) k_bscan(const int* __restrict__ bcount,
                                               int* __restrict__ bptr,
                                               int* __restrict__ bcursor,
                                               int NB, int E) {
    __shared__ int s[512];
    const int t = threadIdx.x;
    const int v = (t < NB) ? bcount[t] : 0;
    s[t] = v;
    __syncthreads();
#pragma unroll
    for (int off = 1; off < 512; off <<= 1) {
        int u = (t >= off) ? s[t - off] : 0;
        __syncthreads();
        s[t] += u;
        __syncthreads();
    }
    if (t < NB) {
        const int excl = s[t] - v;
        bptr[t] = excl;
        bcursor[t] = excl;
    }
    if (t == NB - 1) bptr[NB] = E;
}

// per-wave hist + per-wave cursors: LDS-atomic contention ~4x lower
__global__ void __launch_bounds__(256) k_bscatter(
        const int* __restrict__ src, const int* __restrict__ dst,
        const float* __restrict__ ew, const int* __restrict__ bptr,
        int* __restrict__ bcursor, int2* __restrict__ bed, int E, int NB) {
    __shared__ int hist4[4][NBMAX];
    __shared__ int cur4[4][NBMAX];
    __shared__ int scn[NBMAX], tot[NBMAX], base[NBMAX];
    __shared__ int2 sorted[CHUNK];
    __shared__ unsigned short bof[CHUNK];
    const int t = threadIdx.x;
    const int w = t >> 6;               // wave id 0..3
    const int c0 = blockIdx.x * CHUNK;
    const int n = (E - c0 < CHUNK) ? (E - c0) : CHUNK;

    for (int l = t; l < NBMAX; l += 256) {
        hist4[0][l] = 0; hist4[1][l] = 0; hist4[2][l] = 0; hist4[3][l] = 0;
    }
    __syncthreads();
    for (int i = t; i < n; i += 256)
        atomicAdd(&hist4[w][((unsigned)dst[c0 + i]) >> 8], 1);
    __syncthreads();
    {   // block totals, inclusive-scan input (2 bins/thread)
        const int l0 = t, l1 = t + 256;
        const int t0 = hist4[0][l0] + hist4[1][l0] + hist4[2][l0] + hist4[3][l0];
        const int t1 = hist4[0][l1] + hist4[1][l1] + hist4[2][l1] + hist4[3][l1];
        tot[l0] = t0; tot[l1] = t1;
        scn[l0] = t0; scn[l1] = t1;
    }
    __syncthreads();
#pragma unroll
    for (int off = 1; off < 512; off <<= 1) {
        const int i1 = t + 256;
        const int v0 = (t >= off) ? scn[t - off] : 0;
        const int v1 = scn[i1 - off];
        __syncthreads();
        scn[t] += v0;
        scn[i1] += v1;
        __syncthreads();
    }
    for (int l = t; l < NBMAX; l += 256) {   // per-wave cursor bases
        int e = scn[l] - tot[l];             // block-exclusive start
        cur4[0][l] = e;
        e += hist4[0][l]; cur4[1][l] = e;
        e += hist4[1][l]; cur4[2][l] = e;
        e += hist4[2][l]; cur4[3][l] = e;
    }
    __syncthreads();
    for (int i = t; i < n; i += 256) {
        const int s  = src[c0 + i];
        const int d  = dst[c0 + i];
        const float wt = ew[c0 + i];
        const int bk = ((unsigned)d) >> 8;
        const int slot = atomicAdd(&cur4[w][bk], 1);
        sorted[slot] = make_int2(s | ((d & 255) << 18), __float_as_int(wt));
        bof[slot] = (unsigned short)bk;
    }
    __syncthreads();
    for (int l = t; l < NB; l += 256)
        base[l] = tot[l] ? atomicAdd(&bcursor[l], tot[l]) : 0;
    __syncthreads();
    for (int i = t; i < n; i += 256) {
        const int bk = bof[i];
        const int excl = scn[bk] - tot[bk];
        bed[base[bk] + (i - excl)] = sorted[i];
    }
}

// ---- pass C: per-bucket sort -> final ed[], rowptr, dis (LDS int atomics) ----
__global__ void __launch_bounds__(256) k_bsort(
        const int2* __restrict__ bed, const int* __restrict__ bptr,
        int* __restrict__ rowptr, float* __restrict__ dis,
        int2* __restrict__ ed, int N, int E, int NB) {
    __shared__ int hist[256], scn[256], cur[256];
    __shared__ float degw[256];
    const int t = threadIdx.x;
    const int b = blockIdx.x;
    const int r0 = b << 8;
    const int L = (N - r0 < 256) ? (N - r0) : 256;
    const int e0 = bptr[b];
    const int M = bptr[b + 1] - e0;

    hist[t] = 0;
    degw[t] = 0.0f;
    __syncthreads();
    for (int i = t; i < M; i += 256) {
        const int2 rec = bed[e0 + i];
        const int dl = ((unsigned)rec.x) >> 18;
        atomicAdd(&hist[dl], 1);
        atomicAdd(&degw[dl], __int_as_float(rec.y));
    }
    __syncthreads();
    scn[t] = hist[t];
    __syncthreads();
#pragma unroll
    for (int off = 1; off < 256; off <<= 1) {
        int u = (t >= off) ? scn[t - off] : 0;
        __syncthreads();
        scn[t] += u;
        __syncthreads();
    }
    const int excl = scn[t] - hist[t];
    if (t < L) {
        rowptr[r0 + t] = e0 + excl;
        dis[r0 + t] = rsqrtf(1.0f + degw[t]);   // self-loop weight 1 => deg >= 1
    }
    cur[t] = excl;
    __syncthreads();
    for (int i = t; i < M; i += 256) {
        const int2 rec = bed[e0 + i];
        const int dl = ((unsigned)rec.x) >> 18;
        const int slot = atomicAdd(&cur[dl], 1);
        ed[e0 + slot] = make_int2(rec.x & 0x3FFFF, rec.y);
    }
    if (b == 0 && t == 0) rowptr[N] = E;
}

// ======================================================================
// Compute kernels (factorized norm: h rows pre-scaled by dis[row])
// ======================================================================

// h1s = (x @ W1) * dis[row] — persistent, double-buffered, reg-staged
__global__ void __launch_bounds__(256, 3) k_gemm1(
        const float* __restrict__ x, const float* __restrict__ W1,
        const float* __restrict__ dis, float* __restrict__ h1s, int N) {
    __shared__ float xs[2][TROWS * XS_PAD];
    __shared__ float W1s[F_IN * H_MID];
    const int t = threadIdx.x;
    for (int i = t; i < F_IN * H_MID; i += 256) W1s[i] = W1[i];
    const int c  = t & 15;
    const int r0 = t >> 4;                 // 0..15; thread owns rows r0, r0+16
    const int ntiles = (N + TROWS - 1) / TROWS;

    float4 st[4];
    auto stage_load = [&](int tile) {
        const float4* xg = reinterpret_cast<const float4*>(x + (long long)tile * TROWS * F_IN);
        const int nfl = ((N - tile * TROWS < TROWS) ? (N - tile * TROWS) : TROWS) * (F_IN / 4);
#pragma unroll
        for (int j = 0; j < 4; ++j) {
            const int i = t + j * 256;
            st[j] = (i < nfl) ? xg[i] : make_float4(0.f, 0.f, 0.f, 0.f);
        }
    };
    auto stage_write = [&](int buf) {
#pragma unroll
        for (int j = 0; j < 4; ++j) {
            const int i = t + j * 256;
            const int r = i >> 5, k4 = i & 31;
            *reinterpret_cast<float4*>(&xs[buf][r * XS_PAD + k4 * 4]) = st[j];
        }
    };

    int tile = blockIdx.x;
    if (tile >= ntiles) return;
    stage_load(tile);
    stage_write(0);
    __syncthreads();
    int buf = 0;
    while (true) {
        const int next = tile + gridDim.x;
        if (next < ntiles) stage_load(next);     // HBM loads in flight during compute
        const float* xr0 = &xs[buf][r0 * XS_PAD];
        const float* xr1 = &xs[buf][(r0 + 16) * XS_PAD];
        float acc0 = 0.0f, acc1 = 0.0f;
#pragma unroll 4
        for (int k4 = 0; k4 < F_IN / 4; ++k4) {
            const float4 v0 = *reinterpret_cast<const float4*>(&xr0[k4 * 4]);
            const float4 v1 = *reinterpret_cast<const float4*>(&xr1[k4 * 4]);
            const float w0 = W1s[(k4 * 4 + 0) * H_MID + c];
            const float w1 = W1s[(k4 * 4 + 1) * H_MID + c];
            const float w2 = W1s[(k4 * 4 + 2) * H_MID + c];
            const float w3 = W1s[(k4 * 4 + 3) * H_MID + c];
            acc0 = fmaf(v0.x, w0, acc0); acc1 = fmaf(v1.x, w0, acc1);
            acc0 = fmaf(v0.y, w1, acc0); acc1 = fmaf(v1.y, w1, acc1);
            acc0 = fmaf(v0.z, w2, acc0); acc1 = fmaf(v1.z, w2, acc1);
            acc0 = fmaf(v0.w, w3, acc0); acc1 = fmaf(v1.w, w3, acc1);
        }
        const long long row0 = (long long)tile * TROWS + r0;
        const long long row1 = row0 + 16;
        if (row0 < N) h1s[row0 * H_MID + c] = acc0 * dis[row0];
        if (row1 < N) h1s[row1 * H_MID + c] = acc1 * dis[row1];
        if (next >= ntiles) break;
        __syncthreads();
        stage_write(buf ^ 1);
        __syncthreads();
        buf ^= 1;
        tile = next;
    }
}

// layer-1 agg + fused gemm2:
//   r_c   = relu(b1[c] + dis[node]*(h1s[node,c] + sum_edges h1s[src,c]*ew))
//   h2s[node,j] = dis[node] * sum_c r_c * W2[c][j]
__global__ void __launch_bounds__(256) k_agg16f(
        const int* __restrict__ rowptr, const int2* __restrict__ ed,
        const float* __restrict__ h, const float* __restrict__ dis,
        const float* __restrict__ b1, const float* __restrict__ W2,
        float* __restrict__ h2s, int N) {
    __shared__ float W2s[H_MID * C_OUT];
    if (threadIdx.x < H_MID * C_OUT) W2s[threadIdx.x] = W2[threadIdx.x];
    __syncthreads();
    const long long tg = (long long)blockIdx.x * 256 + threadIdx.x;
    const int node = (int)(tg >> 4);
    const int c = (int)(tg & 15);
    if (node >= N) return;                    // whole 16-group exits together
    const int beg = rowptr[node];
    const int end = rowptr[node + 1];
    float a0 = h[(long long)node * H_MID + c];   // self loop (weight 1)
    float a1 = 0.f, a2 = 0.f, a3 = 0.f;
    int e = beg;
    for (; e + 3 < end; e += 4) {
        const int2 p0 = ed[e],     p1 = ed[e + 1];
        const int2 p2 = ed[e + 2], p3 = ed[e + 3];
        a0 = fmaf(h[(long long)p0.x * H_MID + c], __int_as_float(p0.y), a0);
        a1 = fmaf(h[(long long)p1.x * H_MID + c], __int_as_float(p1.y), a1);
        a2 = fmaf(h[(long long)p2.x * H_MID + c], __int_as_float(p2.y), a2);
        a3 = fmaf(h[(long long)p3.x * H_MID + c], __int_as_float(p3.y), a3);
    }
    for (; e < end; ++e) {
        const int2 p = ed[e];
        a0 = fmaf(h[(long long)p.x * H_MID + c], __int_as_float(p.y), a0);
    }
    float r = fmaf((a0 + a1) + (a2 + a3), dis[node], b1[c]);
    r = fmaxf(r, 0.0f);                       // fused ReLU (a1 never hits memory)
    // fused gemm2 across the 16-lane group
    float h2 = 0.0f;
#pragma unroll
    for (int cc = 0; cc < H_MID; ++cc) {
        const float rc = __shfl(r, cc, 16);
        h2 = fmaf(rc, W2s[cc * C_OUT + (c & 7)], h2);
    }
    if (c < C_OUT) h2s[(long long)node * C_OUT + c] = h2 * dis[node];
}

// layer-2 agg: out = b2 + dis[node]*(h2s[node] + sum h2s[src]*ew)
__global__ void __launch_bounds__(256) k_agg8(
        const int* __restrict__ rowptr, const int2* __restrict__ ed,
        const float* __restrict__ h, const float* __restrict__ dis,
        const float* __restrict__ b2, float* __restrict__ out, int N) {
    const long long tg = (long long)blockIdx.x * 256 + threadIdx.x;
    const int node = (int)(tg >> 3);
    const int c = (int)(tg & 7);
    if (node >= N) return;
    const int beg = rowptr[node];
    const int end = rowptr[node + 1];
    float a0 = h[(long long)node * C_OUT + c];
    float a1 = 0.f, a2 = 0.f, a3 = 0.f;
    int e = beg;
    for (; e + 3 < end; e += 4) {
        const int2 p0 = ed[e],     p1 = ed[e + 1];
        const int2 p2 = ed[e + 2], p3 = ed[e + 3];
        a0 = fmaf(h[(long long)p0.x * C_OUT + c], __int_as_float(p0.y), a0);
        a1 = fmaf(h[(long long)p1.x * C_OUT + c], __int_as_float(p1.y), a1);
        a2 = fmaf(h[(long long)p2.x * C_OUT + c], __int_as_float(p2.y), a2);
        a3 = fmaf(h[(long long)p3.x * C_OUT + c], __int_as_float(p3.y), a3);
    }
    for (; e < end; ++e) {
        const int2 p = ed[e];
        a0 = fmaf(h[(long long)p.x * C_OUT + c], __int_as_float(p.y), a0);
    }
    out[(long long)node * C_OUT + c] = fmaf((a0 + a1) + (a2 + a3), dis[node], b2[c]);
}

// ======================================================================
// Fallback: atomic pipeline (size-guard escape hatch)
// ======================================================================
__global__ void k_init_deg(float* __restrict__ deg, int N) {
    int i = blockIdx.x * blockDim.x + threadIdx.x;
    if (i < N) deg[i] = 1.0f;
}
__global__ void k_scatter_deg(const int* __restrict__ dst, const float* __restrict__ ew,
                              float* __restrict__ deg, int E) {
    int e = blockIdx.x * blockDim.x + threadIdx.x;
    if (e < E) atomicAdd(&deg[dst[e]], ew[e]);
}
__global__ void k_rsqrt(float* __restrict__ deg, int N) {
    int i = blockIdx.x * blockDim.x + threadIdx.x;
    if (i < N) {
        float v = deg[i];
        deg[i] = (v > 0.0f) ? rsqrtf(v) : 0.0f;
    }
}
__global__ void k_gemm1_r2(const float* __restrict__ x, const float* __restrict__ W1,
                           const float* __restrict__ b1, const float* __restrict__ dis,
                           float* __restrict__ h1, float* __restrict__ a1, int N) {
    __shared__ float W1s[F_IN * H_MID];
    for (int i = threadIdx.x; i < F_IN * H_MID; i += blockDim.x) W1s[i] = W1[i];
    __syncthreads();
    const int c   = threadIdx.x & 15;
    const int lr  = threadIdx.x >> 4;
    const int rpb = blockDim.x >> 4;
    for (long long row = (long long)blockIdx.x * rpb + lr; row < N;
         row += (long long)gridDim.x * rpb) {
        const float4* xr = reinterpret_cast<const float4*>(x + row * F_IN);
        float acc = 0.0f;
#pragma unroll
        for (int k4 = 0; k4 < F_IN / 4; ++k4) {
            float4 v = xr[k4];
            acc = fmaf(v.x, W1s[(k4 * 4 + 0) * H_MID + c], acc);
            acc = fmaf(v.y, W1s[(k4 * 4 + 1) * H_MID + c], acc);
            acc = fmaf(v.z, W1s[(k4 * 4 + 2) * H_MID + c], acc);
            acc = fmaf(v.w, W1s[(k4 * 4 + 3) * H_MID + c], acc);
        }
        h1[row * H_MID + c] = acc;
        float di = dis[row];
        a1[row * H_MID + c] = fmaf(acc, di * di, b1[c]);
    }
}
template <int CH>
__global__ void k_agg_at(const int* __restrict__ src, const int* __restrict__ dst,
                         const float* __restrict__ ew, const float* __restrict__ dis,
                         const float* __restrict__ h, float* __restrict__ out, long long E) {
    const int LOG = (CH == 16) ? 4 : 3;
    const long long total  = E << LOG;
    const long long stride = (long long)gridDim.x * blockDim.x;
    for (long long idx = (long long)blockIdx.x * blockDim.x + threadIdx.x; idx < total;
         idx += stride) {
        const long long e = idx >> LOG;
        const int c = (int)(idx & (CH - 1));
        const int s = src[e];
        const int d = dst[e];
        const float norm = dis[s] * ew[e] * dis[d];
        atomicAdd(out + (long long)d * CH + c, h[(long long)s * CH + c] * norm);
    }
}
__global__ void k_gemm2_r2(const float* __restrict__ a1, const float* __restrict__ W2,
                           const float* __restrict__ b2, const float* __restrict__ dis,
                           float* __restrict__ h2, float* __restrict__ out, int N) {
    __shared__ float W2s[H_MID * C_OUT];
    if (threadIdx.x < H_MID * C_OUT) W2s[threadIdx.x] = W2[threadIdx.x];
    __syncthreads();
    const int c   = threadIdx.x & 7;
    const int lr  = threadIdx.x >> 3;
    const int rpb = blockDim.x >> 3;
    for (long long row = (long long)blockIdx.x * rpb + lr; row < N;
         row += (long long)gridDim.x * rpb) {
        const float4* ar = reinterpret_cast<const float4*>(a1 + row * H_MID);
        float acc = 0.0f;
#pragma unroll
        for (int k4 = 0; k4 < H_MID / 4; ++k4) {
            float4 v = ar[k4];
            acc = fmaf(fmaxf(v.x, 0.0f), W2s[(k4 * 4 + 0) * C_OUT + c], acc);
            acc = fmaf(fmaxf(v.y, 0.0f), W2s[(k4 * 4 + 1) * C_OUT + c], acc);
            acc = fmaf(fmaxf(v.z, 0.0f), W2s[(k4 * 4 + 2) * C_OUT + c], acc);
            acc = fmaf(fmaxf(v.w, 0.0f), W2s[(k4 * 4 + 3) * C_OUT + c], acc);
        }
        h2[row * C_OUT + c] = acc;
        float di = dis[row];
        out[row * C_OUT + c] = fmaf(acc, di * di, b2[c]);
    }
}

extern "C" void kernel_launch(void* const* d_in, const int* in_sizes, int n_in,
                              void* d_out, int out_size, void* d_ws, size_t ws_size,
                              hipStream_t stream) {
    const float* x  = (const float*)d_in[0];
    const int*   ei = (const int*)d_in[1];
    const float* ew = (const float*)d_in[2];
    const float* W1 = (const float*)d_in[3];
    const float* b1 = (const float*)d_in[4];
    const float* W2 = (const float*)d_in[5];
    const float* b2 = (const float*)d_in[6];
    float* out = (float*)d_out;

    const int H   = in_sizes[4];            // 16
    const int Fin = in_sizes[3] / H;        // 128
    const int N   = in_sizes[0] / Fin;      // 100000
    const int E   = in_sizes[2];            // 1600000
    const int* src = ei;
    const int* dst = ei + E;
    (void)n_in; (void)out_size;

    char* ws = (char*)d_ws;
    size_t off = 0;
    auto alloc = [&](size_t bytes) {
        void* p = ws + off;
        off = (off + bytes + 255) & ~(size_t)255;
        return p;
    };
    float* dis    = (float*)alloc((size_t)N * sizeof(float));
    float* h1s    = (float*)alloc((size_t)N * H_MID * sizeof(float));
    int*   rowptr = (int*)alloc(((size_t)N + 1) * sizeof(int));
    int*   bcount = (int*)alloc(NBMAX * sizeof(int));
    int*   bptr   = (int*)alloc((NBMAX + 1) * sizeof(int));
    int*   bcursor= (int*)alloc(NBMAX * sizeof(int));
    int2*  bed    = (int2*)alloc((size_t)E * sizeof(int2));
    int2*  ed     = (int2*)alloc((size_t)E * sizeof(int2));
    // h2s aliases bed (dead after k_bsort)
    float* h2s = (float*)bed;
    const size_t needed = off;

    const int B = 256;
    const int NB = (N + 255) >> 8;
    const bool fast_ok = (needed <= ws_size) && (N <= 131072) && (NB <= NBMAX) &&
                         ((size_t)E * sizeof(int2) >= (size_t)N * C_OUT * sizeof(float));

    if (fast_ok) {
        // ---- CSR build (bucket partition + per-bucket sort) ----
        k_zero512<<<1, 512, 0, stream>>>(bcount);
        k_bhist<<<512, B, 0, stream>>>(dst, bcount, E, NB);
        k_bscan<<<1, 512, 0, stream>>>(bcount, bptr, bcursor, NB, E);
        k_bscatter<<<(E + CHUNK - 1) / CHUNK, B, 0, stream>>>(
            src, dst, ew, bptr, bcursor, bed, E, NB);
        k_bsort<<<NB, B, 0, stream>>>(bed, bptr, rowptr, dis, ed, N, E, NB);
        // ---- layer 1 (+ fused ReLU + fused gemm2) ----
        const int ntiles = (N + TROWS - 1) / TROWS;
        const int g1 = (ntiles < 768) ? ntiles : 768;
        k_gemm1<<<g1, B, 0, stream>>>(x, W1, dis, h1s, N);
        k_agg16f<<<(int)(((long long)N * H_MID + B - 1) / B), B, 0, stream>>>(
            rowptr, ed, h1s, dis, b1, W2, h2s, N);
        // ---- layer 2 ----
        k_agg8<<<(int)(((long long)N * C_OUT + B - 1) / B), B, 0, stream>>>(
            rowptr, ed, h2s, dis, b2, out, N);
    } else {
        // ---- fallback: atomic path (~17 MB) ----
        off = 0;
        float* disF = (float*)alloc((size_t)N * sizeof(float));
        float* h1   = (float*)alloc((size_t)N * H_MID * sizeof(float));
        float* a1F  = (float*)alloc((size_t)N * H_MID * sizeof(float));
        float* h2   = (float*)alloc((size_t)N * C_OUT * sizeof(float));
        k_init_deg<<<(N + B - 1) / B, B, 0, stream>>>(disF, N);
        k_scatter_deg<<<(E + B - 1) / B, B, 0, stream>>>(dst, ew, disF, E);
        k_rsqrt<<<(N + B - 1) / B, B, 0, stream>>>(disF, N);
        k_gemm1_r2<<<(N + 15) / 16, B, 0, stream>>>(x, W1, b1, disF, h1, a1F, N);
        k_agg_at<H_MID><<<8192, B, 0, stream>>>(src, dst, ew, disF, h1, a1F, E);
        k_gemm2_r2<<<(N + 31) / 32, B, 0, stream>>>(a1F, W2, b2, disF, h2, out, N);
        k_agg_at<C_OUT><<<8192, B, 0, stream>>>(src, dst, ew, disF, h2, out, E);
    }
}

// Round 9
// 134.574 us; speedup vs baseline: 1.1594x; 1.0474x over previous
//
#include <hip/hip_runtime.h>

#define F_IN  128
#define H_MID 16
#define C_OUT 8
#define XS_PAD (F_IN + 4)
#define TROWS 32            // gemm1 tile rows (double-buffered)
#define CHUNK 4096          // edges per k_bscatter block
#define NBMAX 512           // bucket array size (NB = ceil(N/256) <= 512)
#define GEMM_SHF (2 * TROWS * XS_PAD + F_IN * H_MID)   // 10496 floats = 41984 B

// ---- zero bcount (cheap kernel; avoids fillBuffer in graph) ----
__global__ void __launch_bounds__(512) k_zero512(int* __restrict__ p) {
    p[threadIdx.x] = 0;
}

// ======================================================================
// gemm1 worker (device fn): h1 = x @ W1 (UNSCALED), tiles [t0,t1) with
// stride S, offset j. Double-buffered LDS staging from a 42KB arena.
// Requires 256-thread blocks. dis is applied later in k_agg16f.
// ======================================================================
__device__ __forceinline__ void gemm1_part(
        const float* __restrict__ x, const float* __restrict__ W1,
        float* __restrict__ h1, int N, int t0, int t1, int j, int S,
        float* __restrict__ arena) {
    float* xs  = arena;                          // [2][TROWS*XS_PAD]
    float* W1s = arena + 2 * TROWS * XS_PAD;     // [F_IN*H_MID]
    const int t = threadIdx.x;
    for (int i = t; i < F_IN * H_MID; i += 256) W1s[i] = W1[i];
    const int c  = t & 15;
    const int r0 = t >> 4;
    int tile = t0 + j;
    if (tile >= t1) return;

    float4 st[4];
    auto stage_load = [&](int tl) {
        const float4* xg = reinterpret_cast<const float4*>(x + (long long)tl * TROWS * F_IN);
        const int nfl = ((N - tl * TROWS < TROWS) ? (N - tl * TROWS) : TROWS) * (F_IN / 4);
#pragma unroll
        for (int k = 0; k < 4; ++k) {
            const int i = t + k * 256;
            st[k] = (i < nfl) ? xg[i] : make_float4(0.f, 0.f, 0.f, 0.f);
        }
    };
    auto stage_write = [&](int buf) {
#pragma unroll
        for (int k = 0; k < 4; ++k) {
            const int i = t + k * 256;
            *reinterpret_cast<float4*>(&xs[buf * TROWS * XS_PAD + (i >> 5) * XS_PAD + (i & 31) * 4]) = st[k];
        }
    };

    stage_load(tile);
    stage_write(0);
    __syncthreads();
    int buf = 0;
    while (true) {
        const int next = tile + S;
        if (next < t1) stage_load(next);
        const float* xr0 = &xs[buf * TROWS * XS_PAD + r0 * XS_PAD];
        const float* xr1 = xr0 + 16 * XS_PAD;
        float acc0 = 0.0f, acc1 = 0.0f;
#pragma unroll 4
        for (int k4 = 0; k4 < F_IN / 4; ++k4) {
            const float4 v0 = *reinterpret_cast<const float4*>(&xr0[k4 * 4]);
            const float4 v1 = *reinterpret_cast<const float4*>(&xr1[k4 * 4]);
            const float w0 = W1s[(k4 * 4 + 0) * H_MID + c];
            const float w1 = W1s[(k4 * 4 + 1) * H_MID + c];
            const float w2 = W1s[(k4 * 4 + 2) * H_MID + c];
            const float w3 = W1s[(k4 * 4 + 3) * H_MID + c];
            acc0 = fmaf(v0.x, w0, acc0); acc1 = fmaf(v1.x, w0, acc1);
            acc0 = fmaf(v0.y, w1, acc0); acc1 = fmaf(v1.y, w1, acc1);
            acc0 = fmaf(v0.z, w2, acc0); acc1 = fmaf(v1.z, w2, acc1);
            acc0 = fmaf(v0.w, w3, acc0); acc1 = fmaf(v1.w, w3, acc1);
        }
        const long long row0 = (long long)tile * TROWS + r0;
        const long long row1 = row0 + 16;
        if (row0 < N) h1[row0 * H_MID + c] = acc0;
        if (row1 < N) h1[row1 * H_MID + c] = acc1;
        if (next >= t1) break;
        __syncthreads();
        stage_write(buf ^ 1);
        __syncthreads();
        buf ^= 1;
        tile = next;
    }
}

// ======================================================================
// CSR build kernels, each with piggybacked gemm1 blocks (blockIdx >= NCSR)
// ======================================================================

__global__ void __launch_bounds__(256) k_bhist_g(
        const int* __restrict__ dst, int* __restrict__ bcount, int E, int NB,
        const float* __restrict__ x, const float* __restrict__ W1,
        float* __restrict__ h1, int N, int t0, int t1, int NCSR, int NG) {
    union Shm { int hist[NBMAX]; float g[GEMM_SHF]; };
    __shared__ Shm u;
    const int b = blockIdx.x;
    if (b >= NCSR) { gemm1_part(x, W1, h1, N, t0, t1, b - NCSR, NG, u.g); return; }
    const int t = threadIdx.x;
    for (int l = t; l < NBMAX; l += 256) u.hist[l] = 0;
    __syncthreads();
    for (int i = b * 256 + t; i < E; i += NCSR * 256)
        atomicAdd(&u.hist[((unsigned)dst[i]) >> 8], 1);
    __syncthreads();
    for (int l = t; l < NB; l += 256)
        if (u.hist[l]) atomicAdd(&bcount[l], u.hist[l]);
}

__global__ void __launch_bounds__(512) k_bscan(const int* __restrict__ bcount,
                                               int* __restrict__ bptr,
                                               int* __restrict__ bcursor,
                                               int NB, int E) {
    __shared__ int s[512];
    const int t = threadIdx.x;
    const int v = (t < NB) ? bcount[t] : 0;
    s[t] = v;
    __syncthreads();
#pragma unroll
    for (int off = 1; off < 512; off <<= 1) {
        int u = (t >= off) ? s[t - off] : 0;
        __syncthreads();
        s[t] += u;
        __syncthreads();
    }
    if (t < NB) {
        const int excl = s[t] - v;
        bptr[t] = excl;
        bcursor[t] = excl;
    }
    if (t == NB - 1) bptr[NB] = E;
}

// per-wave hist + per-wave cursors (round-8 structure) + gemm1 piggyback
__global__ void __launch_bounds__(256) k_bscatter_g(
        const int* __restrict__ src, const int* __restrict__ dst,
        const float* __restrict__ ew, const int* __restrict__ bptr,
        int* __restrict__ bcursor, int2* __restrict__ bed, int E, int NB,
        const float* __restrict__ x, const float* __restrict__ W1,
        float* __restrict__ h1, int N, int t0, int t1, int NCSR, int NG) {
    struct S {
        int hist4[4][NBMAX];
        int cur4[4][NBMAX];
        int scn[NBMAX], tot[NBMAX], base[NBMAX];
        int2 sorted[CHUNK];
        unsigned short bof[CHUNK];
    };
    union Shm { S s; float g[GEMM_SHF]; };
    __shared__ Shm u;
    const int b = blockIdx.x;
    if (b >= NCSR) { gemm1_part(x, W1, h1, N, t0, t1, b - NCSR, NG, u.g); return; }

    const int t = threadIdx.x;
    const int w = t >> 6;               // wave id 0..3
    const int c0 = b * CHUNK;
    const int n = (E - c0 < CHUNK) ? (E - c0) : CHUNK;

    for (int l = t; l < NBMAX; l += 256) {
        u.s.hist4[0][l] = 0; u.s.hist4[1][l] = 0; u.s.hist4[2][l] = 0; u.s.hist4[3][l] = 0;
    }
    __syncthreads();
    for (int i = t; i < n; i += 256)
        atomicAdd(&u.s.hist4[w][((unsigned)dst[c0 + i]) >> 8], 1);
    __syncthreads();
    {
        const int l0 = t, l1 = t + 256;
        const int q0 = u.s.hist4[0][l0] + u.s.hist4[1][l0] + u.s.hist4[2][l0] + u.s.hist4[3][l0];
        const int q1 = u.s.hist4[0][l1] + u.s.hist4[1][l1] + u.s.hist4[2][l1] + u.s.hist4[3][l1];
        u.s.tot[l0] = q0; u.s.tot[l1] = q1;
        u.s.scn[l0] = q0; u.s.scn[l1] = q1;
    }
    __syncthreads();
#pragma unroll
    for (int off = 1; off < 512; off <<= 1) {
        const int i1 = t + 256;
        const int v0 = (t >= off) ? u.s.scn[t - off] : 0;
        const int v1 = u.s.scn[i1 - off];
        __syncthreads();
        u.s.scn[t] += v0;
        u.s.scn[i1] += v1;
        __syncthreads();
    }
    for (int l = t; l < NBMAX; l += 256) {
        int e = u.s.scn[l] - u.s.tot[l];
        u.s.cur4[0][l] = e;
        e += u.s.hist4[0][l]; u.s.cur4[1][l] = e;
        e += u.s.hist4[1][l]; u.s.cur4[2][l] = e;
        e += u.s.hist4[2][l]; u.s.cur4[3][l] = e;
    }
    __syncthreads();
    for (int i = t; i < n; i += 256) {
        const int s  = src[c0 + i];
        const int d  = dst[c0 + i];
        const float wt = ew[c0 + i];
        const int bk = ((unsigned)d) >> 8;
        const int slot = atomicAdd(&u.s.cur4[w][bk], 1);
        u.s.sorted[slot] = make_int2(s | ((d & 255) << 18), __float_as_int(wt));
        u.s.bof[slot] = (unsigned short)bk;
    }
    __syncthreads();
    for (int l = t; l < NB; l += 256)
        u.s.base[l] = u.s.tot[l] ? atomicAdd(&bcursor[l], u.s.tot[l]) : 0;
    __syncthreads();
    for (int i = t; i < n; i += 256) {
        const int bk = u.s.bof[i];
        const int excl = u.s.scn[bk] - u.s.tot[bk];
        bed[u.s.base[bk] + (i - excl)] = u.s.sorted[i];
    }
}

// per-bucket sort -> final ed[], rowptr, dis + gemm1 piggyback
__global__ void __launch_bounds__(256) k_bsort_g(
        const int2* __restrict__ bed, const int* __restrict__ bptr,
        int* __restrict__ rowptr, float* __restrict__ dis,
        int2* __restrict__ ed, int N, int E, int NB,
        const float* __restrict__ x, const float* __restrict__ W1,
        float* __restrict__ h1, int t0, int t1, int NCSR, int NG) {
    struct S { int hist[256], scn[256], cur[256]; float degw[256]; };
    union Shm { S s; float g[GEMM_SHF]; };
    __shared__ Shm u;
    const int b = blockIdx.x;
    if (b >= NCSR) { gemm1_part(x, W1, h1, N, t0, t1, b - NCSR, NG, u.g); return; }

    const int t = threadIdx.x;
    const int r0 = b << 8;
    const int L = (N - r0 < 256) ? (N - r0) : 256;
    const int e0 = bptr[b];
    const int M = bptr[b + 1] - e0;

    u.s.hist[t] = 0;
    u.s.degw[t] = 0.0f;
    __syncthreads();
    for (int i = t; i < M; i += 256) {
        const int2 rec = bed[e0 + i];
        const int dl = ((unsigned)rec.x) >> 18;
        atomicAdd(&u.s.hist[dl], 1);
        atomicAdd(&u.s.degw[dl], __int_as_float(rec.y));
    }
    __syncthreads();
    u.s.scn[t] = u.s.hist[t];
    __syncthreads();
#pragma unroll
    for (int off = 1; off < 256; off <<= 1) {
        int v = (t >= off) ? u.s.scn[t - off] : 0;
        __syncthreads();
        u.s.scn[t] += v;
        __syncthreads();
    }
    const int excl = u.s.scn[t] - u.s.hist[t];
    if (t < L) {
        rowptr[r0 + t] = e0 + excl;
        dis[r0 + t] = rsqrtf(1.0f + u.s.degw[t]);   // self-loop weight 1 => deg >= 1
    }
    u.s.cur[t] = excl;
    __syncthreads();
    for (int i = t; i < M; i += 256) {
        const int2 rec = bed[e0 + i];
        const int dl = ((unsigned)rec.x) >> 18;
        const int slot = atomicAdd(&u.s.cur[dl], 1);
        ed[e0 + slot] = make_int2(rec.x & 0x3FFFF, rec.y);
    }
    if (b == 0 && t == 0) rowptr[N] = E;
}

// ======================================================================
// Aggregation kernels (h1 is UNSCALED; dis applied here)
// ======================================================================

// layer-1 agg + fused ReLU + fused gemm2:
//   r_c = relu(b1[c] + dis[d]*(h1[d,c]*dis[d] + sum h1[s,c]*dis[s]*ew))
//   h2s[d,j] = dis[d] * sum_c r_c * W2[c][j]
__global__ void __launch_bounds__(256) k_agg16f(
        const int* __restrict__ rowptr, const int2* __restrict__ ed,
        const float* __restrict__ h, const float* __restrict__ dis,
        const float* __restrict__ b1, const float* __restrict__ W2,
        float* __restrict__ h2s, int N) {
    __shared__ float W2s[H_MID * C_OUT];
    if (threadIdx.x < H_MID * C_OUT) W2s[threadIdx.x] = W2[threadIdx.x];
    __syncthreads();
    const long long tg = (long long)blockIdx.x * 256 + threadIdx.x;
    const int node = (int)(tg >> 4);
    const int c = (int)(tg & 15);
    if (node >= N) return;
    const int beg = rowptr[node];
    const int end = rowptr[node + 1];
    const float dn = dis[node];
    float a0 = h[(long long)node * H_MID + c] * dn;   // self loop (weight 1, dis[d])
    float a1 = 0.f, a2 = 0.f, a3 = 0.f;
    int e = beg;
    for (; e + 3 < end; e += 4) {
        const int2 p0 = ed[e],     p1 = ed[e + 1];
        const int2 p2 = ed[e + 2], p3 = ed[e + 3];
        const float w0 = __int_as_float(p0.y) * dis[p0.x];
        const float w1 = __int_as_float(p1.y) * dis[p1.x];
        const float w2 = __int_as_float(p2.y) * dis[p2.x];
        const float w3 = __int_as_float(p3.y) * dis[p3.x];
        a0 = fmaf(h[(long long)p0.x * H_MID + c], w0, a0);
        a1 = fmaf(h[(long long)p1.x * H_MID + c], w1, a1);
        a2 = fmaf(h[(long long)p2.x * H_MID + c], w2, a2);
        a3 = fmaf(h[(long long)p3.x * H_MID + c], w3, a3);
    }
    for (; e < end; ++e) {
        const int2 p = ed[e];
        a0 = fmaf(h[(long long)p.x * H_MID + c], __int_as_float(p.y) * dis[p.x], a0);
    }
    float r = fmaf((a0 + a1) + (a2 + a3), dn, b1[c]);
    r = fmaxf(r, 0.0f);                       // fused ReLU
    // fused gemm2 across the 16-lane group
    float h2 = 0.0f;
#pragma unroll
    for (int cc = 0; cc < H_MID; ++cc) {
        const float rc = __shfl(r, cc, 16);
        h2 = fmaf(rc, W2s[cc * C_OUT + (c & 7)], h2);
    }
    if (c < C_OUT) h2s[(long long)node * C_OUT + c] = h2 * dn;
}

// layer-2 agg: out = b2 + dis[d]*(h2s[d] + sum h2s[s]*ew)  (h2s pre-scaled by dis)
__global__ void __launch_bounds__(256) k_agg8(
        const int* __restrict__ rowptr, const int2* __restrict__ ed,
        const float* __restrict__ h, const float* __restrict__ dis,
        const float* __restrict__ b2, float* __restrict__ out, int N) {
    const long long tg = (long long)blockIdx.x * 256 + threadIdx.x;
    const int node = (int)(tg >> 3);
    const int c = (int)(tg & 7);
    if (node >= N) return;
    const int beg = rowptr[node];
    const int end = rowptr[node + 1];
    float a0 = h[(long long)node * C_OUT + c];
    float a1 = 0.f, a2 = 0.f, a3 = 0.f;
    int e = beg;
    for (; e + 3 < end; e += 4) {
        const int2 p0 = ed[e],     p1 = ed[e + 1];
        const int2 p2 = ed[e + 2], p3 = ed[e + 3];
        a0 = fmaf(h[(long long)p0.x * C_OUT + c], __int_as_float(p0.y), a0);
        a1 = fmaf(h[(long long)p1.x * C_OUT + c], __int_as_float(p1.y), a1);
        a2 = fmaf(h[(long long)p2.x * C_OUT + c], __int_as_float(p2.y), a2);
        a3 = fmaf(h[(long long)p3.x * C_OUT + c], __int_as_float(p3.y), a3);
    }
    for (; e < end; ++e) {
        const int2 p = ed[e];
        a0 = fmaf(h[(long long)p.x * C_OUT + c], __int_as_float(p.y), a0);
    }
    out[(long long)node * C_OUT + c] = fmaf((a0 + a1) + (a2 + a3), dis[node], b2[c]);
}

// ======================================================================
// Fallback: atomic pipeline (size-guard escape hatch)
// ======================================================================
__global__ void k_init_deg(float* __restrict__ deg, int N) {
    int i = blockIdx.x * blockDim.x + threadIdx.x;
    if (i < N) deg[i] = 1.0f;
}
__global__ void k_scatter_deg(const int* __restrict__ dst, const float* __restrict__ ew,
                              float* __restrict__ deg, int E) {
    int e = blockIdx.x * blockDim.x + threadIdx.x;
    if (e < E) atomicAdd(&deg[dst[e]], ew[e]);
}
__global__ void k_rsqrt(float* __restrict__ deg, int N) {
    int i = blockIdx.x * blockDim.x + threadIdx.x;
    if (i < N) {
        float v = deg[i];
        deg[i] = (v > 0.0f) ? rsqrtf(v) : 0.0f;
    }
}
__global__ void k_gemm1_r2(const float* __restrict__ x, const float* __restrict__ W1,
                           const float* __restrict__ b1, const float* __restrict__ dis,
                           float* __restrict__ h1, float* __restrict__ a1, int N) {
    __shared__ float W1s[F_IN * H_MID];
    for (int i = threadIdx.x; i < F_IN * H_MID; i += blockDim.x) W1s[i] = W1[i];
    __syncthreads();
    const int c   = threadIdx.x & 15;
    const int lr  = threadIdx.x >> 4;
    const int rpb = blockDim.x >> 4;
    for (long long row = (long long)blockIdx.x * rpb + lr; row < N;
         row += (long long)gridDim.x * rpb) {
        const float4* xr = reinterpret_cast<const float4*>(x + row * F_IN);
        float acc = 0.0f;
#pragma unroll
        for (int k4 = 0; k4 < F_IN / 4; ++k4) {
            float4 v = xr[k4];
            acc = fmaf(v.x, W1s[(k4 * 4 + 0) * H_MID + c], acc);
            acc = fmaf(v.y, W1s[(k4 * 4 + 1) * H_MID + c], acc);
            acc = fmaf(v.z, W1s[(k4 * 4 + 2) * H_MID + c], acc);
            acc = fmaf(v.w, W1s[(k4 * 4 + 3) * H_MID + c], acc);
        }
        h1[row * H_MID + c] = acc;
        float di = dis[row];
        a1[row * H_MID + c] = fmaf(acc, di * di, b1[c]);
    }
}
template <int CH>
__global__ void k_agg_at(const int* __restrict__ src, const int* __restrict__ dst,
                         const float* __restrict__ ew, const float* __restrict__ dis,
                         const float* __restrict__ h, float* __restrict__ out, long long E) {
    const int LOG = (CH == 16) ? 4 : 3;
    const long long total  = E << LOG;
    const long long stride = (long long)gridDim.x * blockDim.x;
    for (long long idx = (long long)blockIdx.x * blockDim.x + threadIdx.x; idx < total;
         idx += stride) {
        const long long e = idx >> LOG;
        const int c = (int)(idx & (CH - 1));
        const int s = src[e];
        const int d = dst[e];
        const float norm = dis[s] * ew[e] * dis[d];
        atomicAdd(out + (long long)d * CH + c, h[(long long)s * CH + c] * norm);
    }
}
__global__ void k_gemm2_r2(const float* __restrict__ a1, const float* __restrict__ W2,
                           const float* __restrict__ b2, const float* __restrict__ dis,
                           float* __restrict__ h2, float* __restrict__ out, int N) {
    __shared__ float W2s[H_MID * C_OUT];
    if (threadIdx.x < H_MID * C_OUT) W2s[threadIdx.x] = W2[threadIdx.x];
    __syncthreads();
    const int c   = threadIdx.x & 7;
    const int lr  = threadIdx.x >> 3;
    const int rpb = blockDim.x >> 3;
    for (long long row = (long long)blockIdx.x * rpb + lr; row < N;
         row += (long long)gridDim.x * rpb) {
        const float4* ar = reinterpret_cast<const float4*>(a1 + row * H_MID);
        float acc = 0.0f;
#pragma unroll
        for (int k4 = 0; k4 < H_MID / 4; ++k4) {
            float4 v = ar[k4];
            acc = fmaf(fmaxf(v.x, 0.0f), W2s[(k4 * 4 + 0) * C_OUT + c], acc);
            acc = fmaf(fmaxf(v.y, 0.0f), W2s[(k4 * 4 + 1) * C_OUT + c], acc);
            acc = fmaf(fmaxf(v.z, 0.0f), W2s[(k4 * 4 + 2) * C_OUT + c], acc);
            acc = fmaf(fmaxf(v.w, 0.0f), W2s[(k4 * 4 + 3) * C_OUT + c], acc);
        }
        h2[row * C_OUT + c] = acc;
        float di = dis[row];
        out[row * C_OUT + c] = fmaf(acc, di * di, b2[c]);
    }
}

extern "C" void kernel_launch(void* const* d_in, const int* in_sizes, int n_in,
                              void* d_out, int out_size, void* d_ws, size_t ws_size,
                              hipStream_t stream) {
    const float* x  = (const float*)d_in[0];
    const int*   ei = (const int*)d_in[1];
    const float* ew = (const float*)d_in[2];
    const float* W1 = (const float*)d_in[3];
    const float* b1 = (const float*)d_in[4];
    const float* W2 = (const float*)d_in[5];
    const float* b2 = (const float*)d_in[6];
    float* out = (float*)d_out;

    const int H   = in_sizes[4];            // 16
    const int Fin = in_sizes[3] / H;        // 128
    const int N   = in_sizes[0] / Fin;      // 100000
    const int E   = in_sizes[2];            // 1600000
    const int* src = ei;
    const int* dst = ei + E;
    (void)n_in; (void)out_size;

    char* ws = (char*)d_ws;
    size_t off = 0;
    auto alloc = [&](size_t bytes) {
        void* p = ws + off;
        off = (off + bytes + 255) & ~(size_t)255;
        return p;
    };
    float* dis    = (float*)alloc((size_t)N * sizeof(float));
    float* h1     = (float*)alloc((size_t)N * H_MID * sizeof(float));
    int*   rowptr = (int*)alloc(((size_t)N + 1) * sizeof(int));
    int*   bcount = (int*)alloc(NBMAX * sizeof(int));
    int*   bptr   = (int*)alloc((NBMAX + 1) * sizeof(int));
    int*   bcursor= (int*)alloc(NBMAX * sizeof(int));
    int2*  bed    = (int2*)alloc((size_t)E * sizeof(int2));
    int2*  ed     = (int2*)alloc((size_t)E * sizeof(int2));
    // h2s aliases bed (dead after k_bsort_g)
    float* h2s = (float*)bed;
    const size_t needed = off;

    const int B = 256;
    const int NB  = (N + 255) >> 8;
    const int NCH = (E + CHUNK - 1) / CHUNK;
    const bool fast_ok = (needed <= ws_size) && (N <= 131072) && (NB <= NBMAX) &&
                         ((size_t)E * sizeof(int2) >= (size_t)N * C_OUT * sizeof(float));

    if (fast_ok) {
        // gemm1 tile split across the three CSR kernels (30/40/30)
        const int ntiles = (N + TROWS - 1) / TROWS;
        const int tA = (int)((long long)ntiles * 3 / 10);
        const int tB = (int)((long long)ntiles * 7 / 10);
        const int GB_H = 256, GB_S = 121, GB_B = 121;

        k_zero512<<<1, 512, 0, stream>>>(bcount);
        k_bhist_g<<<256 + GB_H, B, 0, stream>>>(dst, bcount, E, NB,
                                                x, W1, h1, N, 0, tA, 256, GB_H);
        k_bscan<<<1, 512, 0, stream>>>(bcount, bptr, bcursor, NB, E);
        k_bscatter_g<<<NCH + GB_S, B, 0, stream>>>(src, dst, ew, bptr, bcursor, bed, E, NB,
                                                   x, W1, h1, N, tA, tB, NCH, GB_S);
        k_bsort_g<<<NB + GB_B, B, 0, stream>>>(bed, bptr, rowptr, dis, ed, N, E, NB,
                                               x, W1, h1, tB, ntiles, NB, GB_B);
        // layer 1 (+ fused ReLU + fused gemm2)
        k_agg16f<<<(int)(((long long)N * H_MID + B - 1) / B), B, 0, stream>>>(
            rowptr, ed, h1, dis, b1, W2, h2s, N);
        // layer 2
        k_agg8<<<(int)(((long long)N * C_OUT + B - 1) / B), B, 0, stream>>>(
            rowptr, ed, h2s, dis, b2, out, N);
    } else {
        // fallback: atomic path (~17 MB)
        off = 0;
        float* disF = (float*)alloc((size_t)N * sizeof(float));
        float* h1F  = (float*)alloc((size_t)N * H_MID * sizeof(float));
        float* a1F  = (float*)alloc((size_t)N * H_MID * sizeof(float));
        float* h2   = (float*)alloc((size_t)N * C_OUT * sizeof(float));
        k_init_deg<<<(N + B - 1) / B, B, 0, stream>>>(disF, N);
        k_scatter_deg<<<(E + B - 1) / B, B, 0, stream>>>(dst, ew, disF, E);
        k_rsqrt<<<(N + B - 1) / B, B, 0, stream>>>(disF, N);
        k_gemm1_r2<<<(N + 15) / 16, B, 0, stream>>>(x, W1, b1, disF, h1F, a1F, N);
        k_agg_at<H_MID><<<8192, B, 0, stream>>>(src, dst, ew, disF, h1F, a1F, E);
        k_gemm2_r2<<<(N + 31) / 32, B, 0, stream>>>(a1F, W2, b2, disF, h2, out, N);
        k_agg_at<C_OUT><<<8192, B, 0, stream>>>(src, dst, ew, disF, h2, out, E);
    }
}